// Round 12
// baseline (41.780 us; speedup 1.0000x reference)
//
#include <hip/hip_runtime.h>
#include <hip/hip_fp16.h>

#define D 300
#define NS 256
#define NA 256
#define W 8
#define NROWS 2048    // 256*8
#define NCHUNK 10     // K padded to 10 chunks of 32 (320)

typedef _Float16 half8 __attribute__((ext_vector_type(8)));
typedef float f32x4 __attribute__((ext_vector_type(4)));

// Swizzled operand layout: [rt(128)][c(10)][lane(64)][e(8)] fp16
// lane = lk*16 + lr, where row = rt*16+lr, k = c*32 + lk*8 + e.
__device__ __forceinline__ int swaddr(int rt, int lr, int k4) {
    int c = k4 >> 5, lk = (k4 & 31) >> 3, e = k4 & 7;   // e in {0,4}
    return ((rt * NCHUNK + c) * 64 + lk * 16 + lr) * 8 + e;
}

__device__ __forceinline__ ushort4 cvt4(float4 v) {
    ushort4 h;
    h.x = __half_as_ushort(__float2half(v.x));
    h.y = __half_as_ushort(__float2half(v.y));
    h.z = __half_as_ushort(__float2half(v.z));
    h.w = __half_as_ushort(__float2half(v.w));
    return h;
}

// ---- gather: one wave per row, fp16 (identical to r11) ----
__global__ __launch_bounds__(256) void k_gather(const float* __restrict__ emb,
                                                const int* __restrict__ sen_cats,
                                                const int* __restrict__ ann_cats,
                                                const int* __restrict__ none_idx,
                                                unsigned short* __restrict__ AH,
                                                unsigned short* __restrict__ BH,
                                                float* __restrict__ rsn,
                                                float* __restrict__ ran,
                                                int* __restrict__ sflag) {
    int tid = threadIdx.x;
    int wv = tid >> 6, lane = tid & 63;
    int task = blockIdx.x * 4 + wv;
    bool isSen = task < NROWS;
    int r = isSen ? task : task - NROWS;
    int cat = isSen ? sen_cats[r] : ann_cats[r];
    unsigned short* HI = isSen ? AH : BH;
    int rt = r >> 4, lr = r & 15;

    const float4* src = reinterpret_cast<const float4*>(emb + (size_t)cat * D);
    float4 v0 = src[lane];                 // indices 0..63 of 75
    *reinterpret_cast<ushort4*>(HI + swaddr(rt, lr, lane * 4)) = cvt4(v0);
    double acc = (double)v0.x * v0.x + (double)v0.y * v0.y +
                 (double)v0.z * v0.z + (double)v0.w * v0.w;
    if (lane < 11) {                       // indices 64..74
        float4 v1 = src[lane + 64];
        *reinterpret_cast<ushort4*>(HI + swaddr(rt, lr, (lane + 64) * 4)) = cvt4(v1);
        acc += (double)v1.x * v1.x + (double)v1.y * v1.y +
               (double)v1.z * v1.z + (double)v1.w * v1.w;
    } else if (lane < 16) {                // zero K-pad: k = 300..319
        ushort4 z = {0, 0, 0, 0};
        *reinterpret_cast<ushort4*>(HI + swaddr(rt, lr, (lane + 64) * 4)) = z;
    }
    for (int off = 32; off > 0; off >>= 1) acc += __shfl_down(acc, off, 64);
    if (lane == 0) {
        float rn = (float)(1.0 / sqrt(acc));   // norms ~17, eps unreachable
        if (isSen) {
            rsn[r] = rn;
            sflag[r] = (cat == none_idx[0]) ? 1 : 0;
        } else {
            ran[r] = rn;
        }
    }
}

// ---- sen_wd_emb: one block per category, lanes parallel over D ----
__global__ __launch_bounds__(128) void k_out2(const float* __restrict__ emb,
                                              const int* __restrict__ sen_cats,
                                              float* __restrict__ out2) {
    int b = blockIdx.x, i = threadIdx.x;
    if (i >= 75) return;
    float4 s = make_float4(0.f, 0.f, 0.f, 0.f);
#pragma unroll
    for (int w = 0; w < W; ++w) {          // w-ascending fp32 adds (ref order)
        int cat = sen_cats[b * W + w];
        float4 v = reinterpret_cast<const float4*>(emb + (size_t)cat * D)[i];
        s.x += v.x; s.y += v.y; s.z += v.z; s.w += v.w;
    }
    reinterpret_cast<float4*>(out2 + (size_t)b * D)[i] = s;
}

// ---- main: fp16 MFMA, per-chunk LDS staging (dbuf), fold in LDS ----
__global__ __launch_bounds__(256, 1) void k_main(const unsigned short* __restrict__ AHu,
                                                 const unsigned short* __restrict__ BHu,
                                                 const float* __restrict__ rsn,
                                                 const float* __restrict__ ran,
                                                 const int* __restrict__ sflag,
                                                 float* __restrict__ out) {
    const _Float16* AH = reinterpret_cast<const _Float16*>(AHu);
    const _Float16* BH = reinterpret_cast<const _Float16*>(BHu);

    __shared__ union U {
        struct { _Float16 A[2][8][64][8]; _Float16 B[2][8][64][8]; } s;  // 32 KB
        float cosld[128][128];                                           // 64 KB
    } u;

    int tid = threadIdx.x;
    int wv = tid >> 6, lane = tid & 63;
    int wy = wv >> 1, wx = wv & 1;      // wave's 64x64 quadrant
    int lr = lane & 15;
    int lk = lane >> 4;
    int by = blockIdx.y, bx = blockIdx.x;

    // staging map: thread handles slabs q, q+4, q+8, q+12 at lane sl
    int q = tid >> 6, sl = tid & 63;
    const _Float16* gsrc[4];
#pragma unroll
    for (int j = 0; j < 4; ++j) {
        int i = q + j * 4;                       // slab 0..15
        gsrc[j] = (i < 8)
            ? AH + (((by * 8 + i) * NCHUNK) * 64 + sl) * 8
            : BH + (((bx * 8 + (i - 8)) * NCHUNK) * 64 + sl) * 8;
    }

    float4 rg0[4], rg1[4];   // ping-pong staging regs (chunk even/odd)

#define LOADREG(rg, c)                                                       \
    {                                                                        \
        _Pragma("unroll")                                                    \
        for (int j = 0; j < 4; ++j)                                          \
            rg[j] = *reinterpret_cast<const float4*>(gsrc[j] + (c) * 512);   \
    }
#define DSWRITE(buf, rg)                                                     \
    {                                                                        \
        _Pragma("unroll")                                                    \
        for (int j = 0; j < 4; ++j) {                                        \
            int i = q + j * 4;                                               \
            float4* dp = (i < 8)                                             \
                ? reinterpret_cast<float4*>(&u.s.A[buf][i][sl][0])           \
                : reinterpret_cast<float4*>(&u.s.B[buf][i - 8][sl][0]);      \
            *dp = rg[j];                                                     \
        }                                                                    \
    }

    f32x4 acc[4][4] = {};
    half8 Ah[4], Bh[4];

    LOADREG(rg0, 0);
    LOADREG(rg1, 1);
    DSWRITE(0, rg0);
    __syncthreads();

#pragma unroll
    for (int c = 0; c < NCHUNK; ++c) {
        int cur = c & 1;
        if (c + 1 < NCHUNK) {             // stage next chunk into other buffer
            if (cur == 0) DSWRITE(1, rg1) else DSWRITE(0, rg0)
        }
        if (c + 2 < NCHUNK) {             // refill the reg set just written
            if (cur == 0) LOADREG(rg0, c + 2) else LOADREG(rg1, c + 2)
        }
#pragma unroll
        for (int m = 0; m < 4; ++m)
            Ah[m] = *reinterpret_cast<const half8*>(&u.s.A[cur][wy * 4 + m][lane][0]);
#pragma unroll
        for (int n = 0; n < 4; ++n)
            Bh[n] = *reinterpret_cast<const half8*>(&u.s.B[cur][wx * 4 + n][lane][0]);
#pragma unroll
        for (int m = 0; m < 4; ++m)
#pragma unroll
            for (int n = 0; n < 4; ++n)
                acc[m][n] = __builtin_amdgcn_mfma_f32_16x16x32_f16(Ah[m], Bh[n], acc[m][n], 0, 0, 0);
        __syncthreads();                  // cur reads done; next buffer written
    }

    // epilogue: cosine scale (C/D: col=lane&15, row=(lane>>4)*4+reg) -> LDS
#pragma unroll
    for (int m = 0; m < 4; ++m) {
        int rbase = wy * 64 + m * 16 + lk * 4;
#pragma unroll
        for (int r = 0; r < 4; ++r) {
            int grow = by * 128 + rbase + r;
            float rsv = rsn[grow];
            float fm = sflag[grow] ? 0.f : 1.f;
            float rf = rsv * fm;
#pragma unroll
            for (int n = 0; n < 4; ++n) {
                int lc = wx * 64 + n * 16 + lr;
                float rav = ran[bx * 128 + lc];
                u.cosld[rbase + r][lc] = acc[m][n][r] * rf * rav;
            }
        }
    }
    __syncthreads();

    // order-dependent fold: one (s,a) pair per thread, w-major order
    int pi = tid >> 4, pj = tid & 15;
    float cur = 0.f;
#pragma unroll
    for (int w = 0; w < W; ++w) {
        const float* rowp = &u.cosld[pi * 8 + w][pj * 8];
#pragma unroll
        for (int v = 0; v < W; ++v) {
            float sv = rowp[v];
            cur = (sv >= cur || sv < 0.f) ? sv : cur;
        }
    }
    out[(by * 16 + pi) * NA + (bx * 16 + pj)] = cur;
#undef LOADREG
#undef DSWRITE
}

extern "C" void kernel_launch(void* const* d_in, const int* in_sizes, int n_in,
                              void* d_out, int out_size, void* d_ws, size_t ws_size,
                              hipStream_t stream) {
    const float* emb = (const float*)d_in[0];
    const int* sen = (const int*)d_in[1];
    const int* ann = (const int*)d_in[2];
    const int* none = (const int*)d_in[3];
    float* out = (float*)d_out;

    char* ws = (char*)d_ws;
    unsigned short* AH = (unsigned short*)(ws + 0);          // 2048*320*2 = 1,310,720
    unsigned short* BH = (unsigned short*)(ws + 1310720);    // 1,310,720
    float* rsn = (float*)(ws + 2621440);                     // 8,192
    float* ran = (float*)(ws + 2629632);                     // 8,192
    int* sflag = (int*)(ws + 2637824);                       // 8,192

    hipLaunchKernelGGL(k_gather, dim3(1024), dim3(256), 0, stream,
                       emb, sen, ann, none, AH, BH, rsn, ran, sflag);
    hipLaunchKernelGGL(k_out2, dim3(NS), dim3(128), 0, stream,
                       emb, sen, out + NS * NA);
    hipLaunchKernelGGL(k_main, dim3(16, 16), dim3(256), 0, stream,
                       AH, BH, rsn, ran, sflag, out);
}

// Round 13
// 24.330 us; speedup vs baseline: 1.7172x; 1.7172x over previous
//
#include <hip/hip_runtime.h>
#include <hip/hip_fp16.h>

#define D 300
#define NS 256
#define NA 256
#define W 8
#define NROWS 2048    // 256*8
#define NCHUNK 10     // K padded to 10 chunks of 32 (320)

typedef _Float16 half8 __attribute__((ext_vector_type(8)));
typedef float f32x4 __attribute__((ext_vector_type(4)));

// Swizzled operand layout: [rt(128)][c(10)][lane(64)][e(8)] fp16
// lane = lk*16 + lr, where row = rt*16+lr, k = c*32 + lk*8 + e.
__device__ __forceinline__ int swaddr(int rt, int lr, int k4) {
    int c = k4 >> 5, lk = (k4 & 31) >> 3, e = k4 & 7;   // e in {0,4}
    return ((rt * NCHUNK + c) * 64 + lk * 16 + lr) * 8 + e;
}

__device__ __forceinline__ ushort4 cvt4(float4 v) {
    ushort4 h;
    h.x = __half_as_ushort(__float2half(v.x));
    h.y = __half_as_ushort(__float2half(v.y));
    h.z = __half_as_ushort(__float2half(v.z));
    h.w = __half_as_ushort(__float2half(v.w));
    return h;
}

// ---- gather: one wave per row, fp16 (identical to r11) ----
__global__ __launch_bounds__(256) void k_gather(const float* __restrict__ emb,
                                                const int* __restrict__ sen_cats,
                                                const int* __restrict__ ann_cats,
                                                const int* __restrict__ none_idx,
                                                unsigned short* __restrict__ AH,
                                                unsigned short* __restrict__ BH,
                                                float* __restrict__ rsn,
                                                float* __restrict__ ran,
                                                int* __restrict__ sflag) {
    int tid = threadIdx.x;
    int wv = tid >> 6, lane = tid & 63;
    int task = blockIdx.x * 4 + wv;
    bool isSen = task < NROWS;
    int r = isSen ? task : task - NROWS;
    int cat = isSen ? sen_cats[r] : ann_cats[r];
    unsigned short* HI = isSen ? AH : BH;
    int rt = r >> 4, lr = r & 15;

    const float4* src = reinterpret_cast<const float4*>(emb + (size_t)cat * D);
    float4 v0 = src[lane];                 // indices 0..63 of 75
    *reinterpret_cast<ushort4*>(HI + swaddr(rt, lr, lane * 4)) = cvt4(v0);
    double acc = (double)v0.x * v0.x + (double)v0.y * v0.y +
                 (double)v0.z * v0.z + (double)v0.w * v0.w;
    if (lane < 11) {                       // indices 64..74
        float4 v1 = src[lane + 64];
        *reinterpret_cast<ushort4*>(HI + swaddr(rt, lr, (lane + 64) * 4)) = cvt4(v1);
        acc += (double)v1.x * v1.x + (double)v1.y * v1.y +
               (double)v1.z * v1.z + (double)v1.w * v1.w;
    } else if (lane < 16) {                // zero K-pad: k = 300..319
        ushort4 z = {0, 0, 0, 0};
        *reinterpret_cast<ushort4*>(HI + swaddr(rt, lr, (lane + 64) * 4)) = z;
    }
    for (int off = 32; off > 0; off >>= 1) acc += __shfl_down(acc, off, 64);
    if (lane == 0) {
        float rn = (float)(1.0 / sqrt(acc));   // norms ~17, eps unreachable
        if (isSen) {
            rsn[r] = rn;
            sflag[r] = (cat == none_idx[0]) ? 1 : 0;
        } else {
            ran[r] = rn;
        }
    }
}

// ---- sen_wd_emb: one block per category, lanes parallel over D ----
__global__ __launch_bounds__(128) void k_out2(const float* __restrict__ emb,
                                              const int* __restrict__ sen_cats,
                                              float* __restrict__ out2) {
    int b = blockIdx.x, i = threadIdx.x;
    if (i >= 75) return;
    float4 s = make_float4(0.f, 0.f, 0.f, 0.f);
#pragma unroll
    for (int w = 0; w < W; ++w) {          // w-ascending fp32 adds (ref order)
        int cat = sen_cats[b * W + w];
        float4 v = reinterpret_cast<const float4*>(emb + (size_t)cat * D)[i];
        s.x += v.x; s.y += v.y; s.z += v.z; s.w += v.w;
    }
    reinterpret_cast<float4*>(out2 + (size_t)b * D)[i] = s;
}

// ---- main: r11 loop + conflict-free pair-major epilogue/fold ----
__global__ __launch_bounds__(256, 1) void k_main(const unsigned short* __restrict__ AHu,
                                                 const unsigned short* __restrict__ BHu,
                                                 const float* __restrict__ rsn,
                                                 const float* __restrict__ ran,
                                                 const int* __restrict__ sflag,
                                                 float* __restrict__ out) {
    const _Float16* AH = reinterpret_cast<const _Float16*>(AHu);
    const _Float16* BH = reinterpret_cast<const _Float16*>(BHu);

    // pair-major cos store: pl[pair][ (w&3)*8 + v ], stride 33 (bank-free)
    __shared__ float pl[256][33];   // 33,792 B

    int tid = threadIdx.x;
    int wv = tid >> 6, lane = tid & 63;
    int wy = wv >> 1, wx = wv & 1;      // wave's 64x64 quadrant
    int lr = lane & 15;
    int lk = lane >> 4;
    int by = blockIdx.y, bx = blockIdx.x;

    int aBase[4], bBase[4];
#pragma unroll
    for (int m = 0; m < 4; ++m)
        aBase[m] = (((by * 8 + wy * 4 + m) * NCHUNK) * 64 + lane) * 8;
#pragma unroll
    for (int n = 0; n < 4; ++n)
        bBase[n] = (((bx * 8 + wx * 4 + n) * NCHUNK) * 64 + lane) * 8;

    f32x4 acc[4][4] = {};
    half8 Ah[4], Bh[4];

#pragma unroll
    for (int c = 0; c < NCHUNK; ++c) {
        int co = c * 512;
#pragma unroll
        for (int m = 0; m < 4; ++m)
            Ah[m] = *reinterpret_cast<const half8*>(AH + aBase[m] + co);
#pragma unroll
        for (int n = 0; n < 4; ++n)
            Bh[n] = *reinterpret_cast<const half8*>(BH + bBase[n] + co);
#pragma unroll
        for (int m = 0; m < 4; ++m)
#pragma unroll
            for (int n = 0; n < 4; ++n)
                acc[m][n] = __builtin_amdgcn_mfma_f32_16x16x32_f16(Ah[m], Bh[n], acc[m][n], 0, 0, 0);
    }

    // precompute per-(m,r) row scale and per-n col scale
    // C/D: row = wy*64 + m*16 + lk*4 + r (reg r), col = wx*64 + n*16 + lr
    int lkh = lk >> 1;      // row-octet half within the 16-row m-block
    int lkp = lk & 1;       // phase this lane's rows belong to (w = lkp*4 + r)
    int lrh = lr >> 3, lrv = lr & 7;

    float rowScale[4][4];   // [m][r]
#pragma unroll
    for (int m = 0; m < 4; ++m)
#pragma unroll
        for (int r = 0; r < 4; ++r) {
            int grow = by * 128 + wy * 64 + m * 16 + lk * 4 + r;
            rowScale[m][r] = sflag[grow] ? 0.f : rsn[grow];
        }
    float colScale[4];
#pragma unroll
    for (int n = 0; n < 4; ++n)
        colScale[n] = ran[bx * 128 + wx * 64 + n * 16 + lr];

    float cur = 0.f;
    int pi = tid >> 4, pj = tid & 15;   // fold pair = tid

#pragma unroll
    for (int p = 0; p < 2; ++p) {
        if (p == 1) __syncthreads();    // phase-0 reads done before overwrite
        if (lkp == p) {
#pragma unroll
            for (int m = 0; m < 4; ++m) {
                int prow = wy * 8 + m * 2 + lkh;
#pragma unroll
                for (int n = 0; n < 4; ++n) {
                    int pair = prow * 16 + wx * 8 + n * 2 + lrh;
#pragma unroll
                    for (int r = 0; r < 4; ++r)
                        pl[pair][r * 8 + lrv] = acc[m][n][r] * rowScale[m][r] * colScale[n];
                }
            }
        }
        __syncthreads();
        // fold 32 positions of this phase (w = 4p + j/8, v = j%8), order-preserving
#pragma unroll
        for (int j = 0; j < 32; ++j) {
            float sv = pl[tid][j];
            cur = (sv >= cur || sv < 0.f) ? sv : cur;
        }
    }
    out[(by * 16 + pi) * NA + (bx * 16 + pj)] = cur;
}

extern "C" void kernel_launch(void* const* d_in, const int* in_sizes, int n_in,
                              void* d_out, int out_size, void* d_ws, size_t ws_size,
                              hipStream_t stream) {
    const float* emb = (const float*)d_in[0];
    const int* sen = (const int*)d_in[1];
    const int* ann = (const int*)d_in[2];
    const int* none = (const int*)d_in[3];
    float* out = (float*)d_out;

    char* ws = (char*)d_ws;
    unsigned short* AH = (unsigned short*)(ws + 0);          // 2048*320*2 = 1,310,720
    unsigned short* BH = (unsigned short*)(ws + 1310720);    // 1,310,720
    float* rsn = (float*)(ws + 2621440);                     // 8,192
    float* ran = (float*)(ws + 2629632);                     // 8,192
    int* sflag = (int*)(ws + 2637824);                       // 8,192

    hipLaunchKernelGGL(k_gather, dim3(1024), dim3(256), 0, stream,
                       emb, sen, ann, none, AH, BH, rsn, ran, sflag);
    hipLaunchKernelGGL(k_out2, dim3(NS), dim3(128), 0, stream,
                       emb, sen, out + NS * NA);
    hipLaunchKernelGGL(k_main, dim3(16, 16), dim3(256), 0, stream,
                       AH, BH, rsn, ran, sflag, out);
}